// Round 1
// baseline (280.913 us; speedup 1.0000x reference)
//
#include <hip/hip_runtime.h>
#include <stdint.h>

typedef __attribute__((ext_vector_type(8))) short short8;
typedef __attribute__((ext_vector_type(4))) float f32x4;

#define S_LEN 2048
#define HID 2048
#define NH 16
#define NKV 4
#define DH 128
#define WINDOW 1024
#define SCALE 0.08838834764831845f

__device__ __forceinline__ unsigned short f2bf(float f) {
    unsigned int u = __float_as_uint(f);
    unsigned int r = (u + 0x7fffu + ((u >> 16) & 1u)) >> 16;
    return (unsigned short)r;
}

__device__ __forceinline__ void gload16(const void* g, void* l) {
    __builtin_amdgcn_global_load_lds((__attribute__((address_space(1))) void*)g,
                                     (__attribute__((address_space(3))) void*)l, 16, 0, 0);
}

// ---------------- prep kernels ----------------

__global__ __launch_bounds__(256) void cast4_kernel(const float* __restrict__ src,
                                                    unsigned short* __restrict__ dst, int n4) {
    int i = blockIdx.x * 256 + threadIdx.x;
    if (i < n4) {
        float4 v = ((const float4*)src)[i];
        ushort4 o;
        o.x = f2bf(v.x); o.y = f2bf(v.y); o.z = f2bf(v.z); o.w = f2bf(v.w);
        ((ushort4*)dst)[i] = o;
    }
}

__global__ __launch_bounds__(256) void build_bias_kernel(const float* __restrict__ bq,
                                                         const float* __restrict__ bk,
                                                         const float* __restrict__ bv,
                                                         float* __restrict__ cbias) {
    int i = blockIdx.x * 256 + threadIdx.x;
    if (i < 3072) {
        float v;
        if (i < 2048) v = bq[i];
        else if (i < 2560) v = bk[i - 2048];
        else v = bv[i - 2560];
        cbias[i] = v;
    }
}

// src: K x N (f32), dst: (N x K) bf16 at row offset rowoff, row stride K
__global__ __launch_bounds__(256) void transpose_cast_kernel(const float* __restrict__ src,
                                                             unsigned short* __restrict__ dst,
                                                             int N, int K, int rowoff) {
    __shared__ unsigned short t[32][33];
    int n0 = blockIdx.x * 32, k0 = blockIdx.y * 32;
    int c = threadIdx.x & 31, r8 = threadIdx.x >> 5;
#pragma unroll
    for (int i = 0; i < 4; i++) {
        int r = r8 + i * 8;
        t[r][c] = f2bf(src[(size_t)(k0 + r) * N + n0 + c]);
    }
    __syncthreads();
#pragma unroll
    for (int i = 0; i < 4; i++) {
        int r = r8 + i * 8;
        dst[(size_t)(rowoff + n0 + r) * K + k0 + c] = t[c][r];
    }
}

// ---------------- GEMM: C[M,N] = A[M,K] * Bt[N,K]^T (+bias) ----------------

__global__ __launch_bounds__(256) void gemm_bf16(const unsigned short* __restrict__ A,
                                                 const unsigned short* __restrict__ Bt,
                                                 float* __restrict__ C,
                                                 const float* __restrict__ bias,
                                                 int M, int N, int K) {
    __shared__ unsigned short Al[2][128 * 32];
    __shared__ unsigned short Bl[2][128 * 32];
    const int tid = threadIdx.x;
    const int lane = tid & 63;
    const int w = tid >> 6;
    const int nbn = N >> 7;
    const int bm = blockIdx.x / nbn, bn = blockIdx.x % nbn;
    const int m0 = bm << 7, n0 = bn << 7;
    const int wr = w >> 1, wc = w & 1;

    const int lin0 = tid * 16;
    const int r0 = lin0 >> 6, b0 = lin0 & 63;
    const int lin1 = 4096 + tid * 16;
    const int r1 = lin1 >> 6, b1 = lin1 & 63;
    const size_t Kb = (size_t)K * 2;

    const char* Ab = (const char*)A + (size_t)m0 * Kb;
    const char* Bb = (const char*)Bt + (size_t)n0 * Kb;
    char* Al0 = (char*)&Al[0][0];
    char* Bl0 = (char*)&Bl[0][0];
    const int wb = w * 1024;

    auto stage = [&](int buf, int kt) {
        const char* Ak = Ab + kt * 64;
        const char* Bk = Bb + kt * 64;
        char* Ad = Al0 + buf * 8192;
        char* Bd = Bl0 + buf * 8192;
        gload16(Ak + (size_t)r0 * Kb + b0, Ad + wb);
        gload16(Ak + (size_t)r1 * Kb + b1, Ad + 4096 + wb);
        gload16(Bk + (size_t)r0 * Kb + b0, Bd + wb);
        gload16(Bk + (size_t)r1 * Kb + b1, Bd + 4096 + wb);
    };

    f32x4 acc[4][4] = {};
    const int NT = K >> 5;
    stage(0, 0);
    for (int kt = 0; kt < NT; ++kt) {
        __syncthreads();
        if (kt + 1 < NT) stage((kt + 1) & 1, kt + 1);
        const char* Ar = (const char*)&Al[kt & 1][0];
        const char* Br = (const char*)&Bl[kt & 1][0];
        const int ko = (lane >> 4) * 16;
        short8 af[4], bfr[4];
#pragma unroll
        for (int m = 0; m < 4; m++)
            af[m] = *(const short8*)(Ar + (wr * 64 + m * 16 + (lane & 15)) * 64 + ko);
#pragma unroll
        for (int n = 0; n < 4; n++)
            bfr[n] = *(const short8*)(Br + (wc * 64 + n * 16 + (lane & 15)) * 64 + ko);
#pragma unroll
        for (int m = 0; m < 4; m++)
#pragma unroll
            for (int n = 0; n < 4; n++)
                acc[m][n] = __builtin_amdgcn_mfma_f32_16x16x32_bf16(af[m], bfr[n], acc[m][n], 0, 0, 0);
        __syncthreads();
    }

#pragma unroll
    for (int m = 0; m < 4; m++) {
        const int row = m0 + wr * 64 + m * 16 + (lane >> 4) * 4;
#pragma unroll
        for (int n = 0; n < 4; n++) {
            const int col = n0 + wc * 64 + n * 16 + (lane & 15);
            const float badd = bias ? bias[col] : 0.f;
            float* Cp = C + (size_t)row * N + col;
#pragma unroll
            for (int r = 0; r < 4; r++)
                Cp[(size_t)r * N] = acc[m][n][r] + badd;
        }
    }
}

// ---------------- RoPE + layout ----------------
// qkv: [S][3072] f32  ->  Qr [16][S][128], Kr [4][S][128], Vt [4][128][S] (bf16)
__global__ __launch_bounds__(256) void rope_kernel(const float* __restrict__ qkv,
                                                   unsigned short* __restrict__ Qr,
                                                   unsigned short* __restrict__ Kr,
                                                   unsigned short* __restrict__ Vt) {
    int s = blockIdx.x, tid = threadIdx.x;
    __shared__ float cs[64], sn[64];
    if (tid < 64) {
        float inv = __expf(-(float)tid * (logf(10000.f) / 64.f));
        float ang = (float)s * inv;
        float si, co;
        sincosf(ang, &si, &co);
        cs[tid] = co;
        sn[tid] = si;
    }
    __syncthreads();
    const float* row = qkv + (size_t)s * 3072;
#pragma unroll
    for (int it = 0; it < 8; ++it) {
        int j = tid + it * 256;
        int h = j >> 7, d = j & 127, f = d & 63;
        float x = row[j];
        float other = row[(j & ~127) + (d ^ 64)];
        float v = (d < 64) ? x * cs[f] - other * sn[f] : x * cs[f] + other * sn[f];
        Qr[((size_t)h * S_LEN + s) * 128 + d] = f2bf(v);
    }
#pragma unroll
    for (int it = 0; it < 2; ++it) {
        int j = tid + it * 256;
        int kvh = j >> 7, d = j & 127, f = d & 63;
        float x = row[2048 + j];
        float other = row[2048 + (j & ~127) + (d ^ 64)];
        float v = (d < 64) ? x * cs[f] - other * sn[f] : x * cs[f] + other * sn[f];
        Kr[((size_t)kvh * S_LEN + s) * 128 + d] = f2bf(v);
        float vv = row[2560 + j];
        Vt[((size_t)kvh * 128 + d) * S_LEN + s] = f2bf(vv);
    }
}

// ---------------- flash attention, sliding window, GQA ----------------

__global__ __launch_bounds__(256) void attn_kernel(const unsigned short* __restrict__ Qr,
                                                   const unsigned short* __restrict__ Kr,
                                                   const unsigned short* __restrict__ Vt,
                                                   const float* __restrict__ mg,
                                                   unsigned short* __restrict__ Ao) {
    __shared__ unsigned short Kl[2][64 * 128];  // swizzled rows of 256B
    __shared__ unsigned short Vl[2][128 * 64];  // swizzled rows of 128B
    __shared__ unsigned short Pl[4][16 * 64];   // per-wave, swizzled rows of 128B
    const int tid = threadIdx.x, lane = tid & 63, w = tid >> 6;
    const int h = blockIdx.y, qt = blockIdx.x;
    const int kvh = h >> 2;
    const int q0 = qt * 64;

    const unsigned short* Qb =
        Qr + ((size_t)h * S_LEN + q0 + w * 16 + (lane & 15)) * 128 + (lane >> 4) * 8;
    short8 qf[4];
#pragma unroll
    for (int ks = 0; ks < 4; ++ks) qf[ks] = *(const short8*)(Qb + ks * 32);

    const float gate = 1.f / (1.f + __expf(-mg[h]));
    const float fac = 1.f - gate;

    float mrow[4] = {-INFINITY, -INFINITY, -INFINITY, -INFINITY};
    float lrow[4] = {0.f, 0.f, 0.f, 0.f};
    f32x4 o[8] = {};

    const char* Kg = (const char*)(Kr + (size_t)kvh * S_LEN * 128);
    const char* Vg = (const char*)(Vt + (size_t)kvh * 128 * S_LEN);
    char* Klb = (char*)&Kl[0][0];
    char* Vlb = (char*)&Vl[0][0];
    const int wb = w * 1024;

    auto stage = [&](int buf, int kt) {
        const int k0 = kt * 64;
#pragma unroll
        for (int iss = 0; iss < 4; ++iss) {
            int lin = iss * 4096 + tid * 16;
            int row = lin >> 8;
            int chunk = (lin >> 4) & 15;
            gload16(Kg + (size_t)(k0 + row) * 256 + ((chunk ^ (row & 7)) << 4),
                    Klb + buf * 16384 + iss * 4096 + wb);
            int d = lin >> 7;
            int vchunk = (lin >> 4) & 7;
            gload16(Vg + (size_t)d * (S_LEN * 2) + (size_t)k0 * 2 + ((vchunk ^ (d & 7)) << 4),
                    Vlb + buf * 16384 + iss * 4096 + wb);
        }
    };

    const int t0 = (q0 >= 1023) ? (q0 - 1023) >> 6 : 0;
    stage(0, t0);
    for (int kt = t0; kt <= qt; ++kt) {
        __syncthreads();
        if (kt < qt) stage((kt - t0 + 1) & 1, kt + 1);
        const int buf = (kt - t0) & 1;
        const int k0 = kt * 64;
        const char* Kb = Klb + buf * 16384;
        const char* Vb = Vlb + buf * 16384;

        // QK^T : per wave S-tile 16 q-rows x 64 k-cols
        f32x4 sc[4];
#pragma unroll
        for (int t = 0; t < 4; t++) {
            sc[t] = (f32x4){0.f, 0.f, 0.f, 0.f};
            const int krow = t * 16 + (lane & 15);
#pragma unroll
            for (int ks = 0; ks < 4; ks++) {
                const int chunk = ks * 4 + (lane >> 4);
                short8 kf = *(const short8*)(Kb + krow * 256 + ((chunk ^ (krow & 7)) << 4));
                sc[t] = __builtin_amdgcn_mfma_f32_16x16x32_bf16(qf[ks], kf, sc[t], 0, 0, 0);
            }
        }

        // online softmax
        const int qrow_base = q0 + w * 16 + (lane >> 4) * 4;
        float alpha[4];
        float ps[4][4];
#pragma unroll
        for (int r = 0; r < 4; r++) {
            const int q = qrow_base + r;
            float mt = -INFINITY;
#pragma unroll
            for (int t = 0; t < 4; t++) {
                const int k = k0 + t * 16 + (lane & 15);
                const bool valid = (k <= q) && (q - k < WINDOW);
                float sv = valid ? sc[t][r] * SCALE : -INFINITY;
                ps[t][r] = sv;
                mt = fmaxf(mt, sv);
            }
#pragma unroll
            for (int off = 1; off < 16; off <<= 1) mt = fmaxf(mt, __shfl_xor(mt, off, 64));
            float mn = fmaxf(mrow[r], mt);
            alpha[r] = (mn == -INFINITY) ? 1.f : __expf(mrow[r] - mn);
            float ls = 0.f;
#pragma unroll
            for (int t = 0; t < 4; t++) {
                float p = (ps[t][r] == -INFINITY) ? 0.f : __expf(ps[t][r] - mn);
                ps[t][r] = p;
                ls += p;
            }
#pragma unroll
            for (int off = 1; off < 16; off <<= 1) ls += __shfl_xor(ls, off, 64);
            lrow[r] = lrow[r] * alpha[r] + ls;
            mrow[r] = mn;
        }

        // P -> LDS (bf16, swizzled)
        char* Pw = (char*)&Pl[w][0];
#pragma unroll
        for (int r = 0; r < 4; r++) {
            const int row = (lane >> 4) * 4 + r;
#pragma unroll
            for (int t = 0; t < 4; t++) {
                const int col = t * 16 + (lane & 15);
                const int chunk = col >> 3;
                *(unsigned short*)(Pw + row * 128 + ((chunk ^ (row & 7)) << 4) + (col & 7) * 2) =
                    f2bf(ps[t][r]);
            }
        }
        asm volatile("s_waitcnt lgkmcnt(0)" ::: "memory");
        __builtin_amdgcn_sched_barrier(0);

        // rescale O
#pragma unroll
        for (int n = 0; n < 8; n++)
#pragma unroll
            for (int r = 0; r < 4; r++) o[n][r] *= alpha[r];

        // PV
#pragma unroll
        for (int n = 0; n < 8; n++) {
            const int d = n * 16 + (lane & 15);
#pragma unroll
            for (int ks = 0; ks < 2; ++ks) {
                const int chunk = ks * 4 + (lane >> 4);
                const int prow = lane & 15;
                short8 pa = *(const short8*)(Pw + prow * 128 + ((chunk ^ (prow & 7)) << 4));
                short8 vbf = *(const short8*)(Vb + d * 128 + ((chunk ^ (d & 7)) << 4));
                o[n] = __builtin_amdgcn_mfma_f32_16x16x32_bf16(pa, vbf, o[n], 0, 0, 0);
            }
        }
        __syncthreads();
    }

    // epilogue: out = (1-gate) * local / l
#pragma unroll
    for (int r = 0; r < 4; r++) {
        const int s = q0 + w * 16 + (lane >> 4) * 4 + r;
        const float inv = fac / lrow[r];
#pragma unroll
        for (int n = 0; n < 8; n++) {
            const int d = n * 16 + (lane & 15);
            Ao[(size_t)s * 2048 + h * 128 + d] = f2bf(o[n][r] * inv);
        }
    }
}

// ---------------- launch ----------------

extern "C" void kernel_launch(void* const* d_in, const int* in_sizes, int n_in,
                              void* d_out, int out_size, void* d_ws, size_t ws_size,
                              hipStream_t stream) {
    const float* hs = (const float*)d_in[0];
    const float* Wq = (const float*)d_in[1];
    const float* bq = (const float*)d_in[2];
    const float* Wk = (const float*)d_in[3];
    const float* bk = (const float*)d_in[4];
    const float* Wv = (const float*)d_in[5];
    const float* bv = (const float*)d_in[6];
    const float* Wo = (const float*)d_in[7];
    const float* mg = (const float*)d_in[8];

    char* ws = (char*)d_ws;
    // region layout (bytes); region0/region1 are reused once their first tenant dies
    unsigned short* hsb   = (unsigned short*)(ws + 0);          // 8 MB, dead after QKV gemm
    unsigned short* woT   = (unsigned short*)(ws + 0);          // reuses hsb region
    unsigned short* wqkvT = (unsigned short*)(ws + 8388608);    // 12 MB, dead after QKV gemm
    unsigned short* attnb = (unsigned short*)(ws + 8388608);    // reuses wqkvT region (8 MB)
    float*          qkvf  = (float*)(ws + 20971520);            // 24 MB
    unsigned short* Qrb   = (unsigned short*)(ws + 46137344);   // 8 MB
    unsigned short* Krb   = (unsigned short*)(ws + 54525952);   // 2 MB
    unsigned short* Vtb   = (unsigned short*)(ws + 56623104);   // 2 MB
    float*          cbias = (float*)(ws + 58720256);            // 12 KB

    // prep
    cast4_kernel<<<4096, 256, 0, stream>>>(hs, hsb, 1048576);
    build_bias_kernel<<<12, 256, 0, stream>>>(bq, bk, bv, cbias);
    transpose_cast_kernel<<<dim3(64, 64), 256, 0, stream>>>(Wq, wqkvT, 2048, 2048, 0);
    transpose_cast_kernel<<<dim3(16, 64), 256, 0, stream>>>(Wk, wqkvT, 512, 2048, 2048);
    transpose_cast_kernel<<<dim3(16, 64), 256, 0, stream>>>(Wv, wqkvT, 512, 2048, 2560);

    // QKV projection: [2048,2048] x [2048,3072] (+bias)
    gemm_bf16<<<16 * 24, 256, 0, stream>>>(hsb, wqkvT, qkvf, cbias, 2048, 3072, 2048);

    // Wo transpose into region0 (hsb now dead)
    transpose_cast_kernel<<<dim3(64, 64), 256, 0, stream>>>(Wo, woT, 2048, 2048, 0);

    // RoPE + layouts
    rope_kernel<<<2048, 256, 0, stream>>>(qkvf, Qrb, Krb, Vtb);

    // attention (writes attnb into region1; wqkvT dead)
    attn_kernel<<<dim3(32, 16), 256, 0, stream>>>(Qrb, Krb, Vtb, mg, attnb);

    // output projection -> d_out (f32)
    gemm_bf16<<<16 * 16, 256, 0, stream>>>(attnb, woT, (float*)d_out, nullptr, 2048, 2048, 2048);
}